// Round 7
// baseline (45.119 us; speedup 1.0000x reference)
//
#include <hip/hip_runtime.h>
#include <hip/hip_bf16.h>

#define NUM_C  16
#define NUM_D  8
#define RECEPT 512
#define LROW   32768
#define EPS_V  1e-4f

// per-slice LDS: 32 windows * 256 stride + 256 overlap = 8448 fp32 = 2112 chunks
#define XBYTES  33792
#define LDS_TOTAL (2 * XBYTES)     // 67584, double-buffered

typedef __attribute__((ext_vector_type(8))) short short8;
typedef __attribute__((ext_vector_type(4))) float f32x4;

__device__ __forceinline__ unsigned short f2bf(float f) {
    unsigned int u = __builtin_bit_cast(unsigned int, f);
    u += 0x7fffu + ((u >> 16) & 1u);   // round-to-nearest-even
    return (unsigned short)(u >> 16);
}

// byte-form involution matching the chunk-form source swizzle q^=(q>>7)&7
__device__ __forceinline__ int bsw(int a) { return a ^ (((a >> 11) & 7) << 4); }

// pack 8 fp32 -> 8 bf16 (RNE); compiler emits v_cvt_pk_bf16_f32
__device__ __forceinline__ short8 cvt8(f32x4 lo, f32x4 hi) {
    union { short8 s; __hip_bfloat162 h[4]; } u;
    u.h[0] = __float22bfloat162_rn(make_float2(lo[0], lo[1]));
    u.h[1] = __float22bfloat162_rn(make_float2(lo[2], lo[3]));
    u.h[2] = __float22bfloat162_rn(make_float2(hi[0], hi[1]));
    u.h[3] = __float22bfloat162_rn(make_float2(hi[2], hi[3]));
    return u.s;
}

// ---------------------------------------------------------------------------
// Prep (16 blocks x 256 thr): per c: G = W W^T + eps I ; chol; Wt = L^{-1} W ;
// store Wt bf16 in MFMA B-fragment order:
//   wfrag[ntile(8)][kk(16)][lane(64)][j(8)]
//   value = Wt[cd = ntile*16 + (lane&15)][r = kk*32 + (lane>>4)*8 + j]
// Also zeroes d_out.
// ---------------------------------------------------------------------------
__global__ void prep_kernel(const float* __restrict__ weight,
                            unsigned short* __restrict__ wfrag,
                            float* __restrict__ out) {
    __shared__ float Wc[NUM_D * RECEPT];
    __shared__ float G[NUM_D][NUM_D];
    __shared__ float Lm[NUM_D][NUM_D];
    const int c = blockIdx.x;
    const int t = threadIdx.x;  // 256 threads

    out[c * 256 + t] = 0.f;
    out[c * 256 + t + 4096] = 0.f;

    const float4* wsrc4 = reinterpret_cast<const float4*>(
        weight + (size_t)c * NUM_D * RECEPT);
    float4* Wc4 = reinterpret_cast<float4*>(Wc);
    #pragma unroll
    for (int i = 0; i < 4; ++i) Wc4[t + i * 256] = wsrc4[t + i * 256];
    __syncthreads();

    if (t < 64) {
        int d = t >> 3, e = t & 7;
        const float4* wd4 = reinterpret_cast<const float4*>(&Wc[d * RECEPT]);
        const float4* we4 = reinterpret_cast<const float4*>(&Wc[e * RECEPT]);
        float s = 0.f;
        #pragma unroll 4
        for (int r4 = 0; r4 < RECEPT / 4; ++r4) {
            float4 a = wd4[r4], bb = we4[r4];
            s += a.x * bb.x + a.y * bb.y + a.z * bb.z + a.w * bb.w;
        }
        if (d == e) s += EPS_V;
        G[d][e] = s;
    }
    __syncthreads();
    if (t == 0) {
        for (int i = 0; i < NUM_D; ++i) {
            float diag = G[i][i];
            for (int k = 0; k < i; ++k) diag -= Lm[i][k] * Lm[i][k];
            float di = sqrtf(diag);
            Lm[i][i] = di;
            float inv = 1.f / di;
            for (int jj = i + 1; jj < NUM_D; ++jj) {
                float s = G[jj][i];
                for (int k = 0; k < i; ++k) s -= Lm[jj][k] * Lm[i][k];
                Lm[jj][i] = s * inv;
            }
        }
    }
    __syncthreads();
    for (int r = t; r < RECEPT; r += 256) {
        float y[NUM_D];
        for (int d = 0; d < NUM_D; ++d) {
            float s = Wc[d * RECEPT + r];
            for (int k = 0; k < d; ++k) s -= Lm[d][k] * y[k];
            y[d] = s / Lm[d][d];
        }
        const int kk = r >> 5;          // 0..15
        const int g  = (r >> 3) & 3;    // k-group within 32
        const int j  = r & 7;
        for (int d = 0; d < NUM_D; ++d) {
            int cd = c * NUM_D + d;
            int ntile = cd >> 4;
            int nl = cd & 15;
            int lane = g * 16 + nl;
            int idx = (((ntile * 16 + kk) * 64) + lane) * 8 + j;
            wfrag[idx] = f2bf(y[d]);
        }
    }
}

// ---------------------------------------------------------------------------
// Main: 512 blocks x 256 thr (4 waves); each block pipelines 4 slices
// (slice id s = bid + 512*t; b = s>>2, quarter qr = s&3) through a
// double-buffered 2x33.8KB LDS with global_load_lds DMA and COUNTED vmcnt
// (prefetch of slice t+1 stays in flight across the barrier -> HBM streams
// continuously under compute). 2 blocks/CU.
// ---------------------------------------------------------------------------
__global__ __launch_bounds__(256, 2) void main_kernel(
        const float* __restrict__ x,
        const unsigned short* __restrict__ wfrag,
        float* __restrict__ out) {
    extern __shared__ char lds[];
    const int bid = blockIdx.x;
    const int t = threadIdx.x;
    const int lane = t & 63;
    const int wv = t >> 6;          // 0..3
    const int rl = lane & 15;
    const int gl = lane >> 4;
    const int nt0 = wv * 2;         // this wave's first ntile

    // stage slice s into buffer bufsel. LDS dest linear (wave-uniform base +
    // lane*16); swizzle lives in the per-lane GLOBAL source chunk index.
    auto stage = [&](int s, int bufsel) {
        char* buf = lds + bufsel * XBYTES;
        const int b = s >> 2, qr = s & 3;
        const char* slice = (const char*)(x + (size_t)b * LROW + qr * 8192);
        #pragma unroll
        for (int i = 0; i < 8; ++i) {
            const int cb = i * 256 + wv * 64;        // wave-uniform chunk base
            const int q = cb + lane;
            const int sq = q ^ ((q >> 7) & 7);
            __builtin_amdgcn_global_load_lds(
                (const __attribute__((address_space(1))) unsigned int*)(slice + sq * 16),
                (__attribute__((address_space(3))) unsigned int*)(buf + cb * 16),
                16, 0, 0);
        }
        if (wv == 0) {   // 64 tail chunks (overlap; wraps to row start, qr==3)
            const char* tsrc = (qr == 3) ? (const char*)(x + (size_t)b * LROW)
                                         : slice + 32768;
            __builtin_amdgcn_global_load_lds(
                (const __attribute__((address_space(1))) unsigned int*)(tsrc + lane * 16),
                (__attribute__((address_space(3))) unsigned int*)(buf + 32768),
                16, 0, 0);
        }
    };

    stage(bid, 0);   // prologue: slice 0 -> buf0

    #pragma unroll 1
    for (int tt = 0; tt < 4; ++tt) {
        const int s = bid + tt * 512;

        if (tt < 3) {
            stage(s + 512, (tt + 1) & 1);   // prefetch next slice, other buf
            // counted wait: drain slice-tt DMAs only, keep tt+1 in flight.
            // wv0 issues 9 DMAs/slice (tail), wv1-3 issue 8.
            if (wv == 0) asm volatile("s_waitcnt vmcnt(9)" ::: "memory");
            else         asm volatile("s_waitcnt vmcnt(8)" ::: "memory");
        } else {
            asm volatile("s_waitcnt vmcnt(0)" ::: "memory");
        }
        __builtin_amdgcn_sched_barrier(0);
        __builtin_amdgcn_s_barrier();       // all waves' slice-tt data landed
        __builtin_amdgcn_sched_barrier(0);

        const char* buf = lds + (tt & 1) * XBYTES;

        f32x4 acc[2][2];
        #pragma unroll
        for (int mi = 0; mi < 2; ++mi)
            #pragma unroll
            for (int ni = 0; ni < 2; ++ni)
                acc[mi][ni] = (f32x4){0.f, 0.f, 0.f, 0.f};

        #pragma unroll 1
        for (int q = 0; q < 4; ++q) {
            // this quarter's B fragments: 8 coalesced b128 from L2
            short8 bq[4][2];
            #pragma unroll
            for (int kkq = 0; kkq < 4; ++kkq)
                #pragma unroll
                for (int ni = 0; ni < 2; ++ni)
                    bq[kkq][ni] = *reinterpret_cast<const short8*>(
                        wfrag + ((size_t)(((nt0 + ni) * 16 + q * 4 + kkq) * 64 + lane)) * 8);

            #pragma unroll
            for (int kkq = 0; kkq < 4; ++kkq) {
                short8 af[2];
                #pragma unroll
                for (int mi = 0; mi < 2; ++mi) {
                    // fragment = 8 consecutive fp32 at window mi*16+rl
                    const int a0 = (mi * 16 + rl) * 1024 + (q * 4 + kkq) * 128 + gl * 32;
                    f32x4 lo = *reinterpret_cast<const f32x4*>(buf + bsw(a0));
                    f32x4 hi = *reinterpret_cast<const f32x4*>(buf + bsw(a0 + 16));
                    af[mi] = cvt8(lo, hi);
                }
                #pragma unroll
                for (int mi = 0; mi < 2; ++mi) {
                    acc[mi][0] = __builtin_amdgcn_mfma_f32_16x16x32_bf16(af[mi], bq[kkq][0], acc[mi][0], 0, 0, 0);
                    acc[mi][1] = __builtin_amdgcn_mfma_f32_16x16x32_bf16(af[mi], bq[kkq][1], acc[mi][1], 0, 0, 0);
                }
            }
        }
        // every ds_read above fed an MFMA (operands consumed) -> safe to
        // barrier without lgkmcnt drain; frees buf for the tt+2 prefetch.
        __builtin_amdgcn_sched_barrier(0);
        __builtin_amdgcn_s_barrier();
        __builtin_amdgcn_sched_barrier(0);

        // epilogue for slice s: q = sum over 8 d-cols of P^2 (lane bits
        // 0..2), sqrt, sum over 32 windows, atomics (mean weight 1/128).
        const int ob = s >> 2;
        #pragma unroll
        for (int ni = 0; ni < 2; ++ni) {
            float ss = 0.f;
            #pragma unroll
            for (int mi = 0; mi < 2; ++mi) {
                #pragma unroll
                for (int r = 0; r < 4; ++r) {
                    float p = acc[mi][ni][r];
                    float qq = p * p;
                    qq += __shfl_xor(qq, 1);
                    qq += __shfl_xor(qq, 2);
                    qq += __shfl_xor(qq, 4);
                    ss += sqrtf(qq);
                }
            }
            ss += __shfl_xor(ss, 16);
            ss += __shfl_xor(ss, 32);
            if (lane < 16 && (lane & 7) == 0) {
                int c = (wv * 32 + ni * 16 + lane) >> 3;
                atomicAdd(&out[ob * NUM_C + c], ss * (1.0f / 128.0f));
            }
        }
    }
}

extern "C" void kernel_launch(void* const* d_in, const int* in_sizes, int n_in,
                              void* d_out, int out_size, void* d_ws, size_t ws_size,
                              hipStream_t stream) {
    (void)in_sizes; (void)n_in; (void)ws_size; (void)out_size;
    const float* x      = (const float*)d_in[0];
    const float* weight = (const float*)d_in[1];
    float* out = (float*)d_out;
    unsigned short* wfrag = (unsigned short*)d_ws;   // needs 128 KiB scratch

    prep_kernel<<<16, 256, 0, stream>>>(weight, wfrag, out);

    hipFuncSetAttribute(reinterpret_cast<const void*>(main_kernel),
                        hipFuncAttributeMaxDynamicSharedMemorySize, LDS_TOTAL);
    main_kernel<<<512, 256, LDS_TOTAL, stream>>>(x, wfrag, out);
}

// Round 8
// 35.269 us; speedup vs baseline: 1.2793x; 1.2793x over previous
//
#include <hip/hip_runtime.h>
#include <hip/hip_bf16.h>

#define NUM_C  16
#define NUM_D  8
#define RECEPT 512
#define LROW   32768
#define EPS_V  1e-4f

// per-block x slice: 32 windows * 256 stride + 256 overlap = 8448 bf16 = 16896 B
#define XBYTES 16896

typedef __attribute__((ext_vector_type(8))) short short8;
typedef __attribute__((ext_vector_type(4))) float f32x4;

__device__ __forceinline__ unsigned short f2bf(float f) {
    unsigned int u = __builtin_bit_cast(unsigned int, f);
    u += 0x7fffu + ((u >> 16) & 1u);   // round-to-nearest-even
    return (unsigned short)(u >> 16);
}

// XOR swizzle on byte address in the bf16 x LDS slice (involution; applied on
// both staging writes and A-fragment reads; breaks the 512B window stride).
__device__ __forceinline__ int xsw(int a) { return a ^ (((a >> 9) & 7) << 4); }

__device__ __forceinline__ ushort4 cvt4(float4 v) {
    ushort4 h;
    h.x = f2bf(v.x); h.y = f2bf(v.y); h.z = f2bf(v.z); h.w = f2bf(v.w);
    return h;
}

// ---------------------------------------------------------------------------
// Prep (16 blocks x 256 thr): per c: G = W W^T + eps I ; chol; Wt = L^{-1} W ;
// store Wt bf16 in MFMA B-fragment order:
//   wfrag[ntile(8)][kk(16)][lane(64)][j(8)]
//   value = Wt[cd = ntile*16 + (lane&15)][r = kk*32 + (lane>>4)*8 + j]
// Also zeroes d_out.
// ---------------------------------------------------------------------------
__global__ void prep_kernel(const float* __restrict__ weight,
                            unsigned short* __restrict__ wfrag,
                            float* __restrict__ out) {
    __shared__ float Wc[NUM_D * RECEPT];
    __shared__ float G[NUM_D][NUM_D];
    __shared__ float Lm[NUM_D][NUM_D];
    const int c = blockIdx.x;
    const int t = threadIdx.x;  // 256 threads

    out[c * 256 + t] = 0.f;
    out[c * 256 + t + 4096] = 0.f;

    const float4* wsrc4 = reinterpret_cast<const float4*>(
        weight + (size_t)c * NUM_D * RECEPT);
    float4* Wc4 = reinterpret_cast<float4*>(Wc);
    #pragma unroll
    for (int i = 0; i < 4; ++i) Wc4[t + i * 256] = wsrc4[t + i * 256];
    __syncthreads();

    if (t < 64) {
        int d = t >> 3, e = t & 7;
        const float4* wd4 = reinterpret_cast<const float4*>(&Wc[d * RECEPT]);
        const float4* we4 = reinterpret_cast<const float4*>(&Wc[e * RECEPT]);
        float s = 0.f;
        #pragma unroll 4
        for (int r4 = 0; r4 < RECEPT / 4; ++r4) {
            float4 a = wd4[r4], bb = we4[r4];
            s += a.x * bb.x + a.y * bb.y + a.z * bb.z + a.w * bb.w;
        }
        if (d == e) s += EPS_V;
        G[d][e] = s;
    }
    __syncthreads();
    if (t == 0) {
        for (int i = 0; i < NUM_D; ++i) {
            float diag = G[i][i];
            for (int k = 0; k < i; ++k) diag -= Lm[i][k] * Lm[i][k];
            float di = sqrtf(diag);
            Lm[i][i] = di;
            float inv = 1.f / di;
            for (int jj = i + 1; jj < NUM_D; ++jj) {
                float s = G[jj][i];
                for (int k = 0; k < i; ++k) s -= Lm[jj][k] * Lm[i][k];
                Lm[jj][i] = s * inv;
            }
        }
    }
    __syncthreads();
    for (int r = t; r < RECEPT; r += 256) {
        float y[NUM_D];
        for (int d = 0; d < NUM_D; ++d) {
            float s = Wc[d * RECEPT + r];
            for (int k = 0; k < d; ++k) s -= Lm[d][k] * y[k];
            y[d] = s / Lm[d][d];
        }
        const int kk = r >> 5;          // 0..15
        const int g  = (r >> 3) & 3;    // k-group within 32
        const int j  = r & 7;
        for (int d = 0; d < NUM_D; ++d) {
            int cd = c * NUM_D + d;
            int ntile = cd >> 4;
            int nl = cd & 15;
            int lane = g * 16 + nl;
            int idx = (((ntile * 16 + kk) * 64) + lane) * 8 + j;
            wfrag[idx] = f2bf(y[d]);
        }
    }
}

// ---------------------------------------------------------------------------
// Main: 2048 blocks (b = bid>>2, quarter qr = bid&3) x 256 thr (4 waves).
// Block tile: 32 windows x 128 cd, K=512. bf16 x slice (16.9 KB LDS) ->
// 4 blocks/CU (VGPR-capped), 16 waves/CU. Staging: 9 float4 loads batched
// into regs (deep HBM queue), then cvt+swizzled LDS write. B fragments from
// L2 with one-quarter lookahead in named register sets (8 loads in flight).
// ---------------------------------------------------------------------------
__global__ __launch_bounds__(256, 4) void main_kernel(
        const float* __restrict__ x,
        const unsigned short* __restrict__ wfrag,
        float* __restrict__ out) {
    __shared__ char lds[XBYTES];
    const int bid = blockIdx.x;
    const int b  = bid >> 2;
    const int qr = bid & 3;
    const int t = threadIdx.x;
    const int lane = t & 63;
    const int wv = t >> 6;          // 0..3
    const int rl = lane & 15;
    const int gl = lane >> 4;
    const int nt0 = wv * 2;         // this wave's first ntile

    const char* slice = (const char*)(x + (size_t)b * LROW + qr * 8192);

    // ---- staging phase 1: issue ALL global loads (deep queue) ----
    float4 va[8], vt;
    #pragma unroll
    for (int i = 0; i < 8; ++i)
        va[i] = *reinterpret_cast<const float4*>(slice + (i * 256 + t) * 16);
    {   // 64 tail chunks (overlap; wraps to row start for qr==3)
        const char* tsrc = (qr == 3) ? (const char*)(x + (size_t)b * LROW)
                                     : slice + 32768;
        if (t < 64) vt = *reinterpret_cast<const float4*>(tsrc + t * 16);
    }
    // ---- staging phase 2: convert + swizzled LDS writes ----
    #pragma unroll
    for (int i = 0; i < 8; ++i) {
        int c8 = (i * 256 + t) * 8;           // bf16 byte base of this chunk
        *reinterpret_cast<ushort4*>(lds + xsw(c8)) = cvt4(va[i]);
    }
    if (t < 64)
        *reinterpret_cast<ushort4*>(lds + xsw((2048 + t) * 8)) = cvt4(vt);

    f32x4 acc[2][2];
    #pragma unroll
    for (int mi = 0; mi < 2; ++mi)
        #pragma unroll
        for (int ni = 0; ni < 2; ++ni)
            acc[mi][ni] = (f32x4){0.f, 0.f, 0.f, 0.f};

    // B-fragment loader for quarter q into a named set (8 coalesced b128)
    short8 bqA[4][2], bqB[4][2];
    auto loadq = [&](short8 (&dst)[4][2], int q) {
        #pragma unroll
        for (int kkq = 0; kkq < 4; ++kkq)
            #pragma unroll
            for (int ni = 0; ni < 2; ++ni)
                dst[kkq][ni] = *reinterpret_cast<const short8*>(
                    wfrag + ((size_t)(((nt0 + ni) * 16 + q * 4 + kkq) * 64 + lane)) * 8);
    };
    auto compute = [&](short8 (&bq)[4][2], int q) {
        #pragma unroll
        for (int kkq = 0; kkq < 4; ++kkq) {
            const int kb = (q * 4 + kkq) * 64 + gl * 16;   // byte offset in k
            short8 af[2];
            #pragma unroll
            for (int mi = 0; mi < 2; ++mi)
                af[mi] = *reinterpret_cast<const short8*>(
                    lds + xsw((mi * 16 + rl) * 512 + kb));
            #pragma unroll
            for (int mi = 0; mi < 2; ++mi) {
                acc[mi][0] = __builtin_amdgcn_mfma_f32_16x16x32_bf16(af[mi], bq[kkq][0], acc[mi][0], 0, 0, 0);
                acc[mi][1] = __builtin_amdgcn_mfma_f32_16x16x32_bf16(af[mi], bq[kkq][1], acc[mi][1], 0, 0, 0);
            }
        }
    };

    loadq(bqA, 0);
    loadq(bqB, 1);          // in flight during q0 compute
    __syncthreads();        // x slice visible to all waves
    compute(bqA, 0);
    loadq(bqA, 2);          // in flight during q1 compute
    compute(bqB, 1);
    loadq(bqB, 3);          // in flight during q2 compute
    compute(bqA, 2);
    compute(bqB, 3);

    // epilogue: q = sum over 8 d-columns of P^2 (lane bits 0..2), sqrt,
    // sum over this block's 32 windows, atomics into out (mean weight 1/128).
    #pragma unroll
    for (int ni = 0; ni < 2; ++ni) {
        float s = 0.f;
        #pragma unroll
        for (int mi = 0; mi < 2; ++mi) {
            #pragma unroll
            for (int r = 0; r < 4; ++r) {
                float p = acc[mi][ni][r];
                float qq = p * p;
                qq += __shfl_xor(qq, 1);
                qq += __shfl_xor(qq, 2);
                qq += __shfl_xor(qq, 4);
                s += sqrtf(qq);
            }
        }
        s += __shfl_xor(s, 16);
        s += __shfl_xor(s, 32);
        if (lane < 16 && (lane & 7) == 0) {
            int c = (wv * 32 + ni * 16 + lane) >> 3;
            atomicAdd(&out[b * NUM_C + c], s * (1.0f / 128.0f));
        }
    }
}

extern "C" void kernel_launch(void* const* d_in, const int* in_sizes, int n_in,
                              void* d_out, int out_size, void* d_ws, size_t ws_size,
                              hipStream_t stream) {
    (void)in_sizes; (void)n_in; (void)ws_size; (void)out_size;
    const float* x      = (const float*)d_in[0];
    const float* weight = (const float*)d_in[1];
    float* out = (float*)d_out;
    unsigned short* wfrag = (unsigned short*)d_ws;   // needs 128 KiB scratch

    prep_kernel<<<16, 256, 0, stream>>>(weight, wfrag, out);
    main_kernel<<<2048, 256, 0, stream>>>(x, wfrag, out);
}

// Round 9
// 33.993 us; speedup vs baseline: 1.3273x; 1.0375x over previous
//
#include <hip/hip_runtime.h>
#include <hip/hip_bf16.h>

#define NUM_C  16
#define NUM_D  8
#define RECEPT 512
#define LROW   32768
#define EPS_V  1e-4f

// per-block x slice: 64 windows * 256 stride + 256 overlap = 16640 bf16
// = 33280 B; +headroom for xsw (sets bits 4-6) -> 33536
#define XBYTES 33536

typedef __attribute__((ext_vector_type(8))) short short8;
typedef __attribute__((ext_vector_type(4))) float f32x4;

__device__ __forceinline__ unsigned short f2bf(float f) {
    unsigned int u = __builtin_bit_cast(unsigned int, f);
    u += 0x7fffu + ((u >> 16) & 1u);   // round-to-nearest-even
    return (unsigned short)(u >> 16);
}

// XOR swizzle on byte address in the bf16 x LDS slice (involution; applied on
// both staging writes and A-fragment reads; breaks the 512B window stride).
__device__ __forceinline__ int xsw(int a) { return a ^ (((a >> 9) & 7) << 4); }

__device__ __forceinline__ ushort4 cvt4(float4 v) {
    ushort4 h;
    h.x = f2bf(v.x); h.y = f2bf(v.y); h.z = f2bf(v.z); h.w = f2bf(v.w);
    return h;
}

// ---------------------------------------------------------------------------
// Prep (16 blocks x 256 thr): per c: G = W W^T + eps I ; chol; Wt = L^{-1} W ;
// store Wt bf16 in MFMA B-fragment order:
//   wfrag[ntile(8)][kk(16)][lane(64)][j(8)]
//   value = Wt[cd = ntile*16 + (lane&15)][r = kk*32 + (lane>>4)*8 + j]
// Also zeroes d_out.
// ---------------------------------------------------------------------------
__global__ void prep_kernel(const float* __restrict__ weight,
                            unsigned short* __restrict__ wfrag,
                            float* __restrict__ out) {
    __shared__ float Wc[NUM_D * RECEPT];
    __shared__ float G[NUM_D][NUM_D];
    __shared__ float Lm[NUM_D][NUM_D];
    const int c = blockIdx.x;
    const int t = threadIdx.x;  // 256 threads

    out[c * 256 + t] = 0.f;
    out[c * 256 + t + 4096] = 0.f;

    const float4* wsrc4 = reinterpret_cast<const float4*>(
        weight + (size_t)c * NUM_D * RECEPT);
    float4* Wc4 = reinterpret_cast<float4*>(Wc);
    #pragma unroll
    for (int i = 0; i < 4; ++i) Wc4[t + i * 256] = wsrc4[t + i * 256];
    __syncthreads();

    if (t < 64) {
        int d = t >> 3, e = t & 7;
        const float4* wd4 = reinterpret_cast<const float4*>(&Wc[d * RECEPT]);
        const float4* we4 = reinterpret_cast<const float4*>(&Wc[e * RECEPT]);
        float s = 0.f;
        #pragma unroll 4
        for (int r4 = 0; r4 < RECEPT / 4; ++r4) {
            float4 a = wd4[r4], bb = we4[r4];
            s += a.x * bb.x + a.y * bb.y + a.z * bb.z + a.w * bb.w;
        }
        if (d == e) s += EPS_V;
        G[d][e] = s;
    }
    __syncthreads();
    if (t == 0) {
        for (int i = 0; i < NUM_D; ++i) {
            float diag = G[i][i];
            for (int k = 0; k < i; ++k) diag -= Lm[i][k] * Lm[i][k];
            float di = sqrtf(diag);
            Lm[i][i] = di;
            float inv = 1.f / di;
            for (int jj = i + 1; jj < NUM_D; ++jj) {
                float s = G[jj][i];
                for (int k = 0; k < i; ++k) s -= Lm[jj][k] * Lm[i][k];
                Lm[jj][i] = s * inv;
            }
        }
    }
    __syncthreads();
    for (int r = t; r < RECEPT; r += 256) {
        float y[NUM_D];
        for (int d = 0; d < NUM_D; ++d) {
            float s = Wc[d * RECEPT + r];
            for (int k = 0; k < d; ++k) s -= Lm[d][k] * y[k];
            y[d] = s / Lm[d][d];
        }
        const int kk = r >> 5;          // 0..15
        const int g  = (r >> 3) & 3;    // k-group within 32
        const int j  = r & 7;
        for (int d = 0; d < NUM_D; ++d) {
            int cd = c * NUM_D + d;
            int ntile = cd >> 4;
            int nl = cd & 15;
            int lane = g * 16 + nl;
            int idx = (((ntile * 16 + kk) * 64) + lane) * 8 + j;
            wfrag[idx] = f2bf(y[d]);
        }
    }
}

// ---------------------------------------------------------------------------
// Main: 1024 blocks (b = bid>>1, half h = bid&1) x 256 thr (4 waves) —
// exactly ONE generation (256 CU x 4 blocks/CU), no block turnover.
// Block tile: 64 windows x 128 cd, K=512. bf16 x slice (33.5 KB LDS, xsw
// swizzle). Staging: 17 float4 issued as one deep batch, then cvt+write.
// Per-wave tile 64x32 (acc[4][2]); B fragments from L2 with one-quarter
// lookahead in named register sets (first quarter issued under staging).
// ---------------------------------------------------------------------------
__global__ __launch_bounds__(256, 4) void main_kernel(
        const float* __restrict__ x,
        const unsigned short* __restrict__ wfrag,
        float* __restrict__ out) {
    __shared__ char lds[XBYTES];
    const int bid = blockIdx.x;
    const int b = bid >> 1;
    const int h = bid & 1;
    const int t = threadIdx.x;
    const int lane = t & 63;
    const int wv = t >> 6;          // 0..3
    const int rl = lane & 15;
    const int gl = lane >> 4;
    const int nt0 = wv * 2;         // this wave's first ntile

    const char* slice = (const char*)(x + (size_t)b * LROW + h * 16384);

    // ---- staging phase 1: issue ALL 17 global loads (deep HBM queue) ----
    float4 va[8], vb[8], vt;
    #pragma unroll
    for (int i = 0; i < 8; ++i)
        va[i] = *reinterpret_cast<const float4*>(slice + (i * 256 + t) * 16);
    #pragma unroll
    for (int i = 0; i < 8; ++i)
        vb[i] = *reinterpret_cast<const float4*>(slice + ((i + 8) * 256 + t) * 16);
    {   // 64 tail chunks (256-elem overlap; wraps to row start for h==1)
        const char* tsrc = h ? (const char*)(x + (size_t)b * LROW)
                             : slice + 65536;
        if (t < 64) vt = *reinterpret_cast<const float4*>(tsrc + t * 16);
    }

    // B-fragment named sets; issue quarter 0 now (L2 latency hides under
    // the cvt+LDS-write phase below).
    short8 bqA[4][2], bqB[4][2];
    auto loadq = [&](short8 (&dst)[4][2], int q) {
        #pragma unroll
        for (int kkq = 0; kkq < 4; ++kkq)
            #pragma unroll
            for (int ni = 0; ni < 2; ++ni)
                dst[kkq][ni] = *reinterpret_cast<const short8*>(
                    wfrag + ((size_t)(((nt0 + ni) * 16 + q * 4 + kkq) * 64 + lane)) * 8);
    };
    loadq(bqA, 0);

    // ---- staging phase 2: convert + swizzled LDS writes ----
    #pragma unroll
    for (int i = 0; i < 8; ++i)
        *reinterpret_cast<ushort4*>(lds + xsw((i * 256 + t) * 8)) = cvt4(va[i]);
    #pragma unroll
    for (int i = 0; i < 8; ++i)
        *reinterpret_cast<ushort4*>(lds + xsw(((i + 8) * 256 + t) * 8)) = cvt4(vb[i]);
    if (t < 64)
        *reinterpret_cast<ushort4*>(lds + xsw((4096 + t) * 8)) = cvt4(vt);

    f32x4 acc[4][2];
    #pragma unroll
    for (int mi = 0; mi < 4; ++mi)
        #pragma unroll
        for (int ni = 0; ni < 2; ++ni)
            acc[mi][ni] = (f32x4){0.f, 0.f, 0.f, 0.f};

    auto compute = [&](short8 (&bq)[4][2], int q) {
        #pragma unroll
        for (int kkq = 0; kkq < 4; ++kkq) {
            const int kb = (q * 4 + kkq) * 64 + gl * 16;   // byte offset in k
            short8 af[4];
            #pragma unroll
            for (int mi = 0; mi < 4; ++mi)
                af[mi] = *reinterpret_cast<const short8*>(
                    lds + xsw((mi * 16 + rl) * 512 + kb));
            #pragma unroll
            for (int mi = 0; mi < 4; ++mi) {
                acc[mi][0] = __builtin_amdgcn_mfma_f32_16x16x32_bf16(af[mi], bq[kkq][0], acc[mi][0], 0, 0, 0);
                acc[mi][1] = __builtin_amdgcn_mfma_f32_16x16x32_bf16(af[mi], bq[kkq][1], acc[mi][1], 0, 0, 0);
            }
        }
    };

    loadq(bqB, 1);          // in flight during q0 compute
    __syncthreads();        // x slice visible to all waves
    compute(bqA, 0);
    loadq(bqA, 2);          // in flight during q1 compute
    compute(bqB, 1);
    loadq(bqB, 3);          // in flight during q2 compute
    compute(bqA, 2);
    compute(bqB, 3);

    // epilogue: q = sum over 8 d-columns of P^2 (lane bits 0..2), sqrt,
    // sum over this block's 64 windows, atomics into out (mean weight 1/128).
    #pragma unroll
    for (int ni = 0; ni < 2; ++ni) {
        float s = 0.f;
        #pragma unroll
        for (int mi = 0; mi < 4; ++mi) {
            #pragma unroll
            for (int r = 0; r < 4; ++r) {
                float p = acc[mi][ni][r];
                float qq = p * p;
                qq += __shfl_xor(qq, 1);
                qq += __shfl_xor(qq, 2);
                qq += __shfl_xor(qq, 4);
                s += sqrtf(qq);
            }
        }
        s += __shfl_xor(s, 16);
        s += __shfl_xor(s, 32);
        if (lane < 16 && (lane & 7) == 0) {
            int c = (wv * 32 + ni * 16 + lane) >> 3;
            atomicAdd(&out[b * NUM_C + c], s * (1.0f / 128.0f));
        }
    }
}

extern "C" void kernel_launch(void* const* d_in, const int* in_sizes, int n_in,
                              void* d_out, int out_size, void* d_ws, size_t ws_size,
                              hipStream_t stream) {
    (void)in_sizes; (void)n_in; (void)ws_size; (void)out_size;
    const float* x      = (const float*)d_in[0];
    const float* weight = (const float*)d_in[1];
    float* out = (float*)d_out;
    unsigned short* wfrag = (unsigned short*)d_ws;   // needs 128 KiB scratch

    prep_kernel<<<16, 256, 0, stream>>>(weight, wfrag, out);
    main_kernel<<<1024, 256, 0, stream>>>(x, wfrag, out);
}